// Round 8
// baseline (138.461 us; speedup 1.0000x reference)
//
#include <hip/hip_runtime.h>
#include <stdint.h>

typedef __attribute__((ext_vector_type(8))) __bf16 bf16x8;
typedef __attribute__((ext_vector_type(4))) float f32x4;

__device__ __forceinline__ unsigned short f2bf(float f) {
  union { float f; unsigned int u; } v; v.f = f;
  unsigned int u = v.u;
  return (unsigned short)((u + 0x7fffu + ((u >> 16) & 1u)) >> 16);
}

#define HAAR(a, bb, cc, dd, oA, oH, oV, oD)                                    \
  oA = 0.5f * ((a + bb) + (cc + dd));                                          \
  oH = 0.5f * ((a + bb) - (cc + dd));                                          \
  oV = 0.5f * ((a - bb) + (cc - dd));                                          \
  oD = 0.5f * ((a - bb) - (cc - dd));

// ---------------- W fp32 -> bf16 (already [N=768][K=768] row-major) --------
__global__ __launch_bounds__(256) void convw_kernel(const float* __restrict__ W,
                                                    unsigned short* __restrict__ Wb) {
  int i = blockIdx.x * 256 + threadIdx.x;  // 147456 threads x 4 floats
  float4 v = ((const float4*)W)[i];
  uint2 o;
  o.x = (unsigned int)f2bf(v.x) | ((unsigned int)f2bf(v.y) << 16);
  o.y = (unsigned int)f2bf(v.z) | ((unsigned int)f2bf(v.w) << 16);
  ((uint2*)Wb)[i] = o;
}

// ------- 2-level Haar DWT -> bf16 A[M=25088][K=768] in patch layout --------
__global__ __launch_bounds__(256) void dwt2_kernel(const float* __restrict__ x,
                                                   unsigned short* __restrict__ A) {
  int tid = blockIdx.x * 256 + threadIdx.x;  // 128*3*56*56 = 1204224
  int J = tid % 56;
  int t = tid / 56;
  int I = t % 56;
  t /= 56;  // t = b*3 + c
  int c = t % 3;
  int b = t / 3;

  const float* xp = x + (((size_t)t * 224 + 4 * I) * 224 + 4 * J);
  float4 r0 = *(const float4*)(xp);
  float4 r1 = *(const float4*)(xp + 224);
  float4 r2 = *(const float4*)(xp + 448);
  float4 r3 = *(const float4*)(xp + 672);

  float A1[2][2], H1[2][2], V1[2][2], D1[2][2];
  HAAR(r0.x, r0.y, r1.x, r1.y, A1[0][0], H1[0][0], V1[0][0], D1[0][0]);
  HAAR(r0.z, r0.w, r1.z, r1.w, A1[0][1], H1[0][1], V1[0][1], D1[0][1]);
  HAAR(r2.x, r2.y, r3.x, r3.y, A1[1][0], H1[1][0], V1[1][0], D1[1][0]);
  HAAR(r2.z, r2.w, r3.z, r3.w, A1[1][1], H1[1][1], V1[1][1], D1[1][1]);

  auto aidx = [&](int y, int xx) -> size_t {
    int mrow = b * 196 + (y >> 4) * 14 + (xx >> 4);
    int k = c * 256 + (y & 15) * 16 + (xx & 15);
    return (size_t)mrow * 768 + (size_t)k;
  };
  auto store2 = [&](int y, int xx, float v0, float v1) {
    unsigned int p = (unsigned int)f2bf(v0) | ((unsigned int)f2bf(v1) << 16);
    *(unsigned int*)(A + aidx(y, xx)) = p;  // xx even -> 4B aligned, same patch
  };

  int y0 = 2 * I, x0 = 2 * J;
  store2(y0,           112 + x0, H1[0][0], H1[0][1]);
  store2(y0 + 1,       112 + x0, H1[1][0], H1[1][1]);
  store2(112 + y0,     x0,       V1[0][0], V1[0][1]);
  store2(112 + y0 + 1, x0,       V1[1][0], V1[1][1]);
  store2(112 + y0,     112 + x0, D1[0][0], D1[0][1]);
  store2(112 + y0 + 1, 112 + x0, D1[1][0], D1[1][1]);

  float vA2, vH2, vV2, vD2;
  HAAR(A1[0][0], A1[0][1], A1[1][0], A1[1][1], vA2, vH2, vV2, vD2);
  A[aidx(I,      J)]      = f2bf(vA2);
  A[aidx(I,      56 + J)] = f2bf(vH2);
  A[aidx(56 + I, J)]      = f2bf(vV2);
  A[aidx(56 + I, 56 + J)] = f2bf(vD2);
}

// --------- bf16 MFMA GEMM: C[M][N] = A[M][K] * Bt[N][K]^T + bias -----------
// M=25088, N=768, K=768. 128x128 block, 4 waves of 64x64 each.
// NO LDS, NO barriers: each wave streams A/B fragments global->reg directly
// (B fully L2-resident at 1.2 MB; A 64B-line coalesced). 4-deep register
// prefetch (lead-3) hides L2/HBM latency; waves are fully independent, so
// no barrier convoy. Full unroll -> constant indices + immediate offsets.
__global__ __launch_bounds__(256, 2) void gemm_kernel(const unsigned short* __restrict__ A,
                                                      const unsigned short* __restrict__ Bt,
                                                      const float* __restrict__ bias,
                                                      float* __restrict__ C) {
  constexpr int K = 768, N = 768;
  constexpr int NT = 24;  // K / 32

  // XCD swizzle: 1176 tiles = 8 XCDs x 147 consecutive tiles (bijective).
  const int orig = blockIdx.x;
  const int tile = (orig & 7) * 147 + (orig >> 3);
  const int bm = tile / 6, bn = tile % 6;

  const int lane = threadIdx.x & 63;
  const int wave = threadIdx.x >> 6;
  const int wr = wave >> 1, wc = wave & 1;
  const int fr = lane & 15;   // fragment row within 16 (A row / B row = C col)
  const int kq = lane >> 4;   // k-quarter (8 bf16 = 16B chunk)

  // per-lane fragment base pointers; per-iter k-offset folds into imm
  const unsigned short* pa[4];
  const unsigned short* pb[4];
#pragma unroll
  for (int i = 0; i < 4; ++i) {
    pa[i] = A + (size_t)(bm * 128 + wr * 64 + i * 16 + fr) * K + kq * 8;
    pb[i] = Bt + (size_t)(bn * 128 + wc * 64 + i * 16 + fr) * K + kq * 8;
  }

  f32x4 acc[4][4] = {};
  bf16x8 av[4][4], bv[4][4];

  // prologue: prefetch k-tiles 0..2 into sets 0..2 (lead-3)
#pragma unroll
  for (int s = 0; s < 3; ++s) {
#pragma unroll
    for (int i = 0; i < 4; ++i) av[s][i] = *(const bf16x8*)(pa[i] + s * 32);
#pragma unroll
    for (int i = 0; i < 4; ++i) bv[s][i] = *(const bf16x8*)(pb[i] + s * 32);
  }

#pragma unroll
  for (int kt = 0; kt < NT; ++kt) {
    const int cur = kt & 3;  // constant under full unroll
    if (kt + 3 < NT) {
      const int nx = (kt + 3) & 3;
#pragma unroll
      for (int i = 0; i < 4; ++i)
        av[nx][i] = *(const bf16x8*)(pa[i] + (kt + 3) * 32);
#pragma unroll
      for (int i = 0; i < 4; ++i)
        bv[nx][i] = *(const bf16x8*)(pb[i] + (kt + 3) * 32);
    }
#pragma unroll
    for (int mi = 0; mi < 4; ++mi)
#pragma unroll
      for (int ni = 0; ni < 4; ++ni)
        acc[mi][ni] = __builtin_amdgcn_mfma_f32_16x16x32_bf16(
            av[cur][mi], bv[cur][ni], acc[mi][ni], 0, 0, 0);
    __builtin_amdgcn_sched_barrier(0);  // pin pipeline shape at iter boundary
  }

  // epilogue: C col = lane&15, row = (lane>>4)*4 + j ; fuse bias
  const int rq = lane >> 4;
  const int mbase = bm * 128, nbase = bn * 128;
#pragma unroll
  for (int ni = 0; ni < 4; ++ni) {
    int n = nbase + wc * 64 + ni * 16 + fr;
    float bb = bias[n];
#pragma unroll
    for (int mi = 0; mi < 4; ++mi) {
      int mrow = mbase + wr * 64 + mi * 16 + rq * 4;
      f32x4 v = acc[mi][ni];
#pragma unroll
      for (int j = 0; j < 4; ++j) C[(size_t)(mrow + j) * N + n] = v[j] + bb;
    }
  }
}

extern "C" void kernel_launch(void* const* d_in, const int* in_sizes, int n_in,
                              void* d_out, int out_size, void* d_ws, size_t ws_size,
                              hipStream_t stream) {
  const float* x = (const float*)d_in[0];     // (128,3,224,224) f32
  const float* W = (const float*)d_in[1];     // (768,3,16,16)  f32
  const float* bias = (const float*)d_in[2];  // (768,)         f32
  float* out = (float*)d_out;                 // (128,196,768)  f32

  unsigned short* A = (unsigned short*)d_ws;                        // 25088*768 bf16
  unsigned short* Wb = (unsigned short*)((char*)d_ws + 38535168);   // 589824 bf16

  convw_kernel<<<576, 256, 0, stream>>>(W, Wb);
  dwt2_kernel<<<4704, 256, 0, stream>>>(x, A);
  gemm_kernel<<<1176, 256, 0, stream>>>(A, Wb, bias, out);
}

// Round 9
// 81.158 us; speedup vs baseline: 1.7061x; 1.7061x over previous
//
#include <hip/hip_runtime.h>
#include <stdint.h>

typedef __attribute__((ext_vector_type(8))) __bf16 bf16x8;
typedef __attribute__((ext_vector_type(4))) float f32x4;

__device__ __forceinline__ unsigned short f2bf(float f) {
  union { float f; unsigned int u; } v; v.f = f;
  unsigned int u = v.u;
  return (unsigned short)((u + 0x7fffu + ((u >> 16) & 1u)) >> 16);
}

__device__ __forceinline__ void async_copy16(const void* g, void* s) {
  __builtin_amdgcn_global_load_lds(
      (__attribute__((address_space(1))) void*)const_cast<void*>(g),
      (__attribute__((address_space(3))) void*)s,
      16, 0, 0);
}

#define HAAR(a, bb, cc, dd, oA, oH, oV, oD)                                    \
  oA = 0.5f * ((a + bb) + (cc + dd));                                          \
  oH = 0.5f * ((a + bb) - (cc + dd));                                          \
  oV = 0.5f * ((a - bb) + (cc - dd));                                          \
  oD = 0.5f * ((a - bb) - (cc - dd));

// ---------------- W fp32 -> bf16 (already [N=768][K=768] row-major) --------
__global__ __launch_bounds__(256) void convw_kernel(const float* __restrict__ W,
                                                    unsigned short* __restrict__ Wb) {
  int i = blockIdx.x * 256 + threadIdx.x;  // 147456 threads x 4 floats
  float4 v = ((const float4*)W)[i];
  uint2 o;
  o.x = (unsigned int)f2bf(v.x) | ((unsigned int)f2bf(v.y) << 16);
  o.y = (unsigned int)f2bf(v.z) | ((unsigned int)f2bf(v.w) << 16);
  ((uint2*)Wb)[i] = o;
}

// ------- 2-level Haar DWT -> bf16 A[M=25088][K=768] in patch layout --------
__global__ __launch_bounds__(256) void dwt2_kernel(const float* __restrict__ x,
                                                   unsigned short* __restrict__ A) {
  int tid = blockIdx.x * 256 + threadIdx.x;  // 128*3*56*56 = 1204224
  int J = tid % 56;
  int t = tid / 56;
  int I = t % 56;
  t /= 56;  // t = b*3 + c
  int c = t % 3;
  int b = t / 3;

  const float* xp = x + (((size_t)t * 224 + 4 * I) * 224 + 4 * J);
  float4 r0 = *(const float4*)(xp);
  float4 r1 = *(const float4*)(xp + 224);
  float4 r2 = *(const float4*)(xp + 448);
  float4 r3 = *(const float4*)(xp + 672);

  float A1[2][2], H1[2][2], V1[2][2], D1[2][2];
  HAAR(r0.x, r0.y, r1.x, r1.y, A1[0][0], H1[0][0], V1[0][0], D1[0][0]);
  HAAR(r0.z, r0.w, r1.z, r1.w, A1[0][1], H1[0][1], V1[0][1], D1[0][1]);
  HAAR(r2.x, r2.y, r3.x, r3.y, A1[1][0], H1[1][0], V1[1][0], D1[1][0]);
  HAAR(r2.z, r2.w, r3.z, r3.w, A1[1][1], H1[1][1], V1[1][1], D1[1][1]);

  auto aidx = [&](int y, int xx) -> size_t {
    int mrow = b * 196 + (y >> 4) * 14 + (xx >> 4);
    int k = c * 256 + (y & 15) * 16 + (xx & 15);
    return (size_t)mrow * 768 + (size_t)k;
  };
  auto store2 = [&](int y, int xx, float v0, float v1) {
    unsigned int p = (unsigned int)f2bf(v0) | ((unsigned int)f2bf(v1) << 16);
    *(unsigned int*)(A + aidx(y, xx)) = p;  // xx even -> 4B aligned, same patch
  };

  int y0 = 2 * I, x0 = 2 * J;
  store2(y0,           112 + x0, H1[0][0], H1[0][1]);
  store2(y0 + 1,       112 + x0, H1[1][0], H1[1][1]);
  store2(112 + y0,     x0,       V1[0][0], V1[0][1]);
  store2(112 + y0 + 1, x0,       V1[1][0], V1[1][1]);
  store2(112 + y0,     112 + x0, D1[0][0], D1[0][1]);
  store2(112 + y0 + 1, 112 + x0, D1[1][0], D1[1][1]);

  float vA2, vH2, vV2, vD2;
  HAAR(A1[0][0], A1[0][1], A1[1][0], A1[1][1], vA2, vH2, vV2, vD2);
  A[aidx(I,      J)]      = f2bf(vA2);
  A[aidx(I,      56 + J)] = f2bf(vH2);
  A[aidx(56 + I, J)]      = f2bf(vV2);
  A[aidx(56 + I, 56 + J)] = f2bf(vD2);
}

// --------- bf16 MFMA GEMM: C[M][N] = A[M][K] * Bt[N][K]^T + bias -----------
// M=25088, N=768, K=768. 8-PHASE TEMPLATE PORT (m201-style):
// BM=256, BN=128, BK=64, 512 threads = 8 waves (4M x 2N, wave-tile 64x64).
// Triple-buffered K64 tiles (144 KB LDS, 1 block/CU). 12 K-tiles; 4 phases
// per tile: {stage 1-2 gloads | ds_reads -> barrier -> lgkmcnt(0) ->
// sched_barrier(0) -> setprio(1) -> 8 MFMA -> setprio(0) -> barrier}.
// Tile-boundary counted vmcnt(6) (t+1 landed, t+2 in flight).
// XOR swizzle over 8 chunks/row: P(row)=row&7 (8 lanes/chunk per read).
__global__ __launch_bounds__(512, 2) void gemm_kernel(const unsigned short* __restrict__ A,
                                                      const unsigned short* __restrict__ Bt,
                                                      const float* __restrict__ bias,
                                                      float* __restrict__ C) {
  constexpr int K = 768, N = 768;
  constexpr int NT = 12;  // K / 64
  __shared__ unsigned short As[3][256 * 64];  // 32 KB per buffer
  __shared__ unsigned short Bs[3][128 * 64];  // 16 KB per buffer

  // bijective XCD swizzle: 588 = 8*73 + 4 (m204 formula, q=73, r=4)
  const int orig = blockIdx.x;
  const int xcd = orig & 7, idx = orig >> 3;
  const int wgid = (xcd < 4 ? xcd * 74 : 296 + (xcd - 4) * 73) + idx;
  const int bm = wgid / 6, bn = wgid % 6;

  const int tid = threadIdx.x;
  const int lane = tid & 63;
  const int wave = tid >> 6;   // 0..7
  const int wm = wave >> 1;    // 0..3 -> rows wm*64..+64
  const int wn = wave & 1;     // 0..1 -> cols wn*64..+64
  const int mbase = bm * 256, nbase = bn * 128;

  f32x4 acc[4][4] = {};

  // --- staging geometry: row stride 128B (64 bf16), 8 chunks of 16B ---
  // dest (per inst i): linear, wave covers 1KB; phys chunk = lane&7,
  // row&7 = (lane>>3)&7 -> source logical chunk lc = phys ^ (row&7).
  const int lc = (lane & 7) ^ ((lane >> 3) & 7);
  const int srow = wave * 8 + (lane >> 3);  // + inst*64
  const unsigned short* gA[4];
  const unsigned short* gB[2];
#pragma unroll
  for (int i = 0; i < 4; ++i) gA[i] = A + (size_t)(mbase + i * 64 + srow) * K + lc * 8;
#pragma unroll
  for (int j = 0; j < 2; ++j) gB[j] = Bt + (size_t)(nbase + j * 64 + srow) * K + lc * 8;

  auto stA = [&](int i, int buf, int kt) {
    async_copy16(gA[i] + kt * 64, (char*)As + buf * 32768 + i * 8192 + wave * 1024);
  };
  auto stB = [&](int j, int buf, int kt) {
    async_copy16(gB[j] + kt * 64, (char*)Bs + buf * 16384 + j * 8192 + wave * 1024);
  };

  // --- fragment read geometry: row = (sub)*16 + fr, chunk = (s*4+kq)^(fr&7)
  const int fr = lane & 15;
  const int kq = lane >> 4;
  const int ch0 = ((kq) ^ (fr & 7)) * 16;      // k-step 0
  const int ch1 = ((4 + kq) ^ (fr & 7)) * 16;  // k-step 1

  // prologue: stage tiles 0,1 (12 loads); wait tile 0 (6 left flying)
  stA(0, 0, 0); stA(1, 0, 0); stA(2, 0, 0); stA(3, 0, 0); stB(0, 0, 0); stB(1, 0, 0);
  stA(0, 1, 1); stA(1, 1, 1); stA(2, 1, 1); stA(3, 1, 1); stB(0, 1, 1); stB(1, 1, 1);
  asm volatile("s_waitcnt vmcnt(6)" ::: "memory");
  __builtin_amdgcn_s_barrier();

#pragma unroll
  for (int kt = 0; kt < NT; ++kt) {
    const int c = kt % 3, cs = (kt + 2) % 3;
    const bool st = (kt + 2) < NT;
    const char* paw = (const char*)As + c * 32768 + (wm * 64 + fr) * 128;
    const char* pbw = (const char*)Bs + c * 16384 + (wn * 64 + fr) * 128;
    bf16x8 af[4], bv[4];

    // ---------------- phase 0: stage A0,A1 | read bv(s0), af01(s0) | 8 MFMA
    if (st) { stA(0, cs, kt + 2); stA(1, cs, kt + 2); }
#pragma unroll
    for (int ni = 0; ni < 4; ++ni) bv[ni] = *(const bf16x8*)(pbw + ni * 2048 + ch0);
    af[0] = *(const bf16x8*)(paw + ch0);
    af[1] = *(const bf16x8*)(paw + 2048 + ch0);
    __builtin_amdgcn_s_barrier();
    asm volatile("s_waitcnt lgkmcnt(0)" ::: "memory");
    __builtin_amdgcn_sched_barrier(0);
    __builtin_amdgcn_s_setprio(1);
#pragma unroll
    for (int mi = 0; mi < 2; ++mi)
#pragma unroll
      for (int ni = 0; ni < 4; ++ni)
        acc[mi][ni] = __builtin_amdgcn_mfma_f32_16x16x32_bf16(af[mi], bv[ni],
                                                              acc[mi][ni], 0, 0, 0);
    __builtin_amdgcn_s_setprio(0);
    __builtin_amdgcn_s_barrier();

    // ---------------- phase 1: stage A2,A3 | read af23(s0) | 8 MFMA
    if (st) { stA(2, cs, kt + 2); stA(3, cs, kt + 2); }
    af[2] = *(const bf16x8*)(paw + 2 * 2048 + ch0);
    af[3] = *(const bf16x8*)(paw + 3 * 2048 + ch0);
    __builtin_amdgcn_s_barrier();
    asm volatile("s_waitcnt lgkmcnt(0)" ::: "memory");
    __builtin_amdgcn_sched_barrier(0);
    __builtin_amdgcn_s_setprio(1);
#pragma unroll
    for (int mi = 2; mi < 4; ++mi)
#pragma unroll
      for (int ni = 0; ni < 4; ++ni)
        acc[mi][ni] = __builtin_amdgcn_mfma_f32_16x16x32_bf16(af[mi], bv[ni],
                                                              acc[mi][ni], 0, 0, 0);
    __builtin_amdgcn_s_setprio(0);
    __builtin_amdgcn_s_barrier();

    // ---------------- phase 2: stage B0 | read bv(s1), af01(s1) | 8 MFMA
    if (st) stB(0, cs, kt + 2);
#pragma unroll
    for (int ni = 0; ni < 4; ++ni) bv[ni] = *(const bf16x8*)(pbw + ni * 2048 + ch1);
    af[0] = *(const bf16x8*)(paw + ch1);
    af[1] = *(const bf16x8*)(paw + 2048 + ch1);
    __builtin_amdgcn_s_barrier();
    asm volatile("s_waitcnt lgkmcnt(0)" ::: "memory");
    __builtin_amdgcn_sched_barrier(0);
    __builtin_amdgcn_s_setprio(1);
#pragma unroll
    for (int mi = 0; mi < 2; ++mi)
#pragma unroll
      for (int ni = 0; ni < 4; ++ni)
        acc[mi][ni] = __builtin_amdgcn_mfma_f32_16x16x32_bf16(af[mi], bv[ni],
                                                              acc[mi][ni], 0, 0, 0);
    __builtin_amdgcn_s_setprio(0);
    __builtin_amdgcn_s_barrier();

    // ---------------- phase 3: stage B1 | read af23(s1) | 8 MFMA | vmcnt
    if (st) stB(1, cs, kt + 2);
    af[2] = *(const bf16x8*)(paw + 2 * 2048 + ch1);
    af[3] = *(const bf16x8*)(paw + 3 * 2048 + ch1);
    __builtin_amdgcn_s_barrier();
    asm volatile("s_waitcnt lgkmcnt(0)" ::: "memory");
    __builtin_amdgcn_sched_barrier(0);
    __builtin_amdgcn_s_setprio(1);
#pragma unroll
    for (int mi = 2; mi < 4; ++mi)
#pragma unroll
      for (int ni = 0; ni < 4; ++ni)
        acc[mi][ni] = __builtin_amdgcn_mfma_f32_16x16x32_bf16(af[mi], bv[ni],
                                                              acc[mi][ni], 0, 0, 0);
    __builtin_amdgcn_s_setprio(0);
    if (kt < NT - 1) {
      if (st)
        asm volatile("s_waitcnt vmcnt(6)" ::: "memory");   // tile kt+1 landed
      else
        asm volatile("s_waitcnt vmcnt(0)" ::: "memory");   // drain at tail
      __builtin_amdgcn_s_barrier();
    }
  }

  // epilogue: C col = lane&15, row = (lane>>4)*4 + j ; fuse bias
  const int rq = lane >> 4;
#pragma unroll
  for (int ni = 0; ni < 4; ++ni) {
    int n = nbase + wn * 64 + ni * 16 + fr;
    float bb = bias[n];
#pragma unroll
    for (int mi = 0; mi < 4; ++mi) {
      int mrow = mbase + wm * 64 + mi * 16 + rq * 4;
      f32x4 v = acc[mi][ni];
#pragma unroll
      for (int j = 0; j < 4; ++j) C[(size_t)(mrow + j) * N + n] = v[j] + bb;
    }
  }
}

extern "C" void kernel_launch(void* const* d_in, const int* in_sizes, int n_in,
                              void* d_out, int out_size, void* d_ws, size_t ws_size,
                              hipStream_t stream) {
  const float* x = (const float*)d_in[0];     // (128,3,224,224) f32
  const float* W = (const float*)d_in[1];     // (768,3,16,16)  f32
  const float* bias = (const float*)d_in[2];  // (768,)         f32
  float* out = (float*)d_out;                 // (128,196,768)  f32

  unsigned short* A = (unsigned short*)d_ws;                        // 25088*768 bf16
  unsigned short* Wb = (unsigned short*)((char*)d_ws + 38535168);   // 589824 bf16

  convw_kernel<<<576, 256, 0, stream>>>(W, Wb);
  dwt2_kernel<<<4704, 256, 0, stream>>>(x, A);
  gemm_kernel<<<588, 512, 0, stream>>>(A, Wb, bias, out);
}

// Round 10
// 66.925 us; speedup vs baseline: 2.0689x; 1.2127x over previous
//
#include <hip/hip_runtime.h>
#include <stdint.h>

typedef __attribute__((ext_vector_type(8))) __bf16 bf16x8;
typedef __attribute__((ext_vector_type(4))) float f32x4;

__device__ __forceinline__ unsigned short f2bf(float f) {
  union { float f; unsigned int u; } v; v.f = f;
  unsigned int u = v.u;
  return (unsigned short)((u + 0x7fffu + ((u >> 16) & 1u)) >> 16);
}

__device__ __forceinline__ void async_copy16(const void* g, void* s) {
  __builtin_amdgcn_global_load_lds(
      (__attribute__((address_space(1))) void*)const_cast<void*>(g),
      (__attribute__((address_space(3))) void*)s,
      16, 0, 0);
}

#define HAAR(a, bb, cc, dd, oA, oH, oV, oD)                                    \
  oA = 0.5f * ((a + bb) + (cc + dd));                                          \
  oH = 0.5f * ((a + bb) - (cc + dd));                                          \
  oV = 0.5f * ((a - bb) + (cc - dd));                                          \
  oD = 0.5f * ((a - bb) - (cc - dd));

// ---------------- W fp32 -> bf16 (already [N=768][K=768] row-major) --------
__global__ __launch_bounds__(256) void convw_kernel(const float* __restrict__ W,
                                                    unsigned short* __restrict__ Wb) {
  int i = blockIdx.x * 256 + threadIdx.x;  // 147456 threads x 4 floats
  float4 v = ((const float4*)W)[i];
  uint2 o;
  o.x = (unsigned int)f2bf(v.x) | ((unsigned int)f2bf(v.y) << 16);
  o.y = (unsigned int)f2bf(v.z) | ((unsigned int)f2bf(v.w) << 16);
  ((uint2*)Wb)[i] = o;
}

// ------- 2-level Haar DWT -> bf16 A[M=25088][K=768] in patch layout --------
__global__ __launch_bounds__(256) void dwt2_kernel(const float* __restrict__ x,
                                                   unsigned short* __restrict__ A) {
  int tid = blockIdx.x * 256 + threadIdx.x;  // 128*3*56*56 = 1204224
  int J = tid % 56;
  int t = tid / 56;
  int I = t % 56;
  t /= 56;  // t = b*3 + c
  int c = t % 3;
  int b = t / 3;

  const float* xp = x + (((size_t)t * 224 + 4 * I) * 224 + 4 * J);
  float4 r0 = *(const float4*)(xp);
  float4 r1 = *(const float4*)(xp + 224);
  float4 r2 = *(const float4*)(xp + 448);
  float4 r3 = *(const float4*)(xp + 672);

  float A1[2][2], H1[2][2], V1[2][2], D1[2][2];
  HAAR(r0.x, r0.y, r1.x, r1.y, A1[0][0], H1[0][0], V1[0][0], D1[0][0]);
  HAAR(r0.z, r0.w, r1.z, r1.w, A1[0][1], H1[0][1], V1[0][1], D1[0][1]);
  HAAR(r2.x, r2.y, r3.x, r3.y, A1[1][0], H1[1][0], V1[1][0], D1[1][0]);
  HAAR(r2.z, r2.w, r3.z, r3.w, A1[1][1], H1[1][1], V1[1][1], D1[1][1]);

  auto aidx = [&](int y, int xx) -> size_t {
    int mrow = b * 196 + (y >> 4) * 14 + (xx >> 4);
    int k = c * 256 + (y & 15) * 16 + (xx & 15);
    return (size_t)mrow * 768 + (size_t)k;
  };
  auto store2 = [&](int y, int xx, float v0, float v1) {
    unsigned int p = (unsigned int)f2bf(v0) | ((unsigned int)f2bf(v1) << 16);
    *(unsigned int*)(A + aidx(y, xx)) = p;  // xx even -> 4B aligned, same patch
  };

  int y0 = 2 * I, x0 = 2 * J;
  store2(y0,           112 + x0, H1[0][0], H1[0][1]);
  store2(y0 + 1,       112 + x0, H1[1][0], H1[1][1]);
  store2(112 + y0,     x0,       V1[0][0], V1[0][1]);
  store2(112 + y0 + 1, x0,       V1[1][0], V1[1][1]);
  store2(112 + y0,     112 + x0, D1[0][0], D1[0][1]);
  store2(112 + y0 + 1, 112 + x0, D1[1][0], D1[1][1]);

  float vA2, vH2, vV2, vD2;
  HAAR(A1[0][0], A1[0][1], A1[1][0], A1[1][1], vA2, vH2, vV2, vD2);
  A[aidx(I,      J)]      = f2bf(vA2);
  A[aidx(I,      56 + J)] = f2bf(vH2);
  A[aidx(56 + I, J)]      = f2bf(vV2);
  A[aidx(56 + I, 56 + J)] = f2bf(vD2);
}

// --------- bf16 MFMA GEMM: C[M][N] = A[M][K] * Bt[N][K]^T + bias -----------
// M=25088, N=768, K=768. r3 geometry: 128x128 block, BK=32, 4 waves 64x64.
// Triple-buffered LDS + REGISTER fragment double-buffer: tile t+1's frags
// are ds_read during tile t's MFMA, so the post-barrier path starts with
// MFMA (not ds_read latency). One barrier/iter, counted vmcnt, r3 swizzle.
__global__ __launch_bounds__(256) void gemm_kernel(const unsigned short* __restrict__ A,
                                                   const unsigned short* __restrict__ Bt,
                                                   const float* __restrict__ bias,
                                                   float* __restrict__ C) {
  constexpr int K = 768, N = 768;
  constexpr int NT = 24;  // K / 32
  __shared__ unsigned short As[3][128 * 32];  // 8 KB per buffer
  __shared__ unsigned short Bs[3][128 * 32];

  // XCD swizzle: 1176 tiles = 8 XCDs x 147 consecutive tiles (bijective).
  const int orig = blockIdx.x;
  const int tile = (orig & 7) * 147 + (orig >> 3);
  const int bm = tile / 6, bn = tile % 6;

  const int tid = threadIdx.x;
  const int lane = tid & 63;
  const int wave = tid >> 6;
  const int wr = wave >> 1, wc = wave & 1;
  const int mbase = bm * 128, nbase = bn * 128;

  f32x4 acc[4][4] = {};

  // staging (r3 exact): phys (row0, chunk kc0); source chunk pre-swizzled.
  const int off0 = wave * 1024 + lane * 16;
  const int row0 = off0 >> 6;                    // 0..63
  const int kc0 = (off0 >> 4) & 3;
  const int kcs = kc0 ^ ((row0 >> 1) & 3);       // swizzled source chunk
  const unsigned short* ga0 = A + (size_t)(mbase + row0) * K + kcs * 8;
  const unsigned short* ga1 = ga0 + (size_t)64 * K;
  const unsigned short* gb0 = Bt + (size_t)(nbase + row0) * K + kcs * 8;
  const unsigned short* gb1 = gb0 + (size_t)64 * K;

  auto stage = [&](int buf, int kt) {
    char* sa = (char*)As + buf * 8192 + wave * 1024;
    char* sb = (char*)Bs + buf * 8192 + wave * 1024;
    const int ko = kt * 32;
    async_copy16(ga0 + ko, sa);
    async_copy16(ga1 + ko, sa + 4096);
    async_copy16(gb0 + ko, sb);
    async_copy16(gb1 + ko, sb + 4096);
  };

  // fragment geometry (r3 exact, conflict-free verified)
  const int fr = lane & 15;
  const int kq = lane >> 4;
  const int chq = kq ^ ((fr >> 1) & 3);
  const int aoff = (wr * 64 + fr) * 64 + chq * 16;  // byte offset in buffer
  const int boff = (wc * 64 + fr) * 64 + chq * 16;

  auto loadfrags = [&](int buf, bf16x8 (&af)[4], bf16x8 (&bv)[4]) {
    const char* pa = (const char*)As + buf * 8192 + aoff;
    const char* pb = (const char*)Bs + buf * 8192 + boff;
#pragma unroll
    for (int i = 0; i < 4; ++i) af[i] = *(const bf16x8*)(pa + i * 1024);
#pragma unroll
    for (int i = 0; i < 4; ++i) bv[i] = *(const bf16x8*)(pb + i * 1024);
  };

  bf16x8 afE[4], bvE[4], afO[4], bvO[4];  // even/odd register frag sets

  // prologue: stage tiles 0,1; tile0 -> even regs
  stage(0, 0);
  stage(1, 1);
  asm volatile("s_waitcnt vmcnt(4)" ::: "memory");  // tile 0 landed
  __builtin_amdgcn_s_barrier();
  loadfrags(0, afE, bvE);

#pragma unroll
  for (int kt = 0; kt < NT; ++kt) {
    if (kt + 2 < NT) {
      stage((kt + 2) % 3, kt + 2);
      asm volatile("s_waitcnt vmcnt(4)" ::: "memory");  // tile kt+1 landed
    } else if (kt + 1 < NT) {
      asm volatile("s_waitcnt vmcnt(0)" ::: "memory");  // last tile landed
    }
    asm volatile("s_waitcnt lgkmcnt(0)" ::: "memory");  // my prev reads done
    __builtin_amdgcn_s_barrier();  // buf[(kt+2)%3] safe to overwrite; kt+1 visible

    bf16x8 (&afC)[4] = (kt & 1) ? afO : afE;
    bf16x8 (&bvC)[4] = (kt & 1) ? bvO : bvE;
    bf16x8 (&afN)[4] = (kt & 1) ? afE : afO;
    bf16x8 (&bvN)[4] = (kt & 1) ? bvE : bvO;

    if (kt + 1 < NT) loadfrags((kt + 1) % 3, afN, bvN);  // prefetch next frags

#pragma unroll
    for (int mi = 0; mi < 4; ++mi)
#pragma unroll
      for (int ni = 0; ni < 4; ++ni)
        acc[mi][ni] = __builtin_amdgcn_mfma_f32_16x16x32_bf16(afC[mi], bvC[ni],
                                                              acc[mi][ni], 0, 0, 0);
  }

  // epilogue: C col = lane&15, row = (lane>>4)*4 + j ; fuse bias
  const int rq = lane >> 4;
#pragma unroll
  for (int ni = 0; ni < 4; ++ni) {
    int n = nbase + wc * 64 + ni * 16 + fr;
    float bb = bias[n];
#pragma unroll
    for (int mi = 0; mi < 4; ++mi) {
      int mrow = mbase + wr * 64 + mi * 16 + rq * 4;
      f32x4 v = acc[mi][ni];
#pragma unroll
      for (int j = 0; j < 4; ++j) C[(size_t)(mrow + j) * N + n] = v[j] + bb;
    }
  }
}

extern "C" void kernel_launch(void* const* d_in, const int* in_sizes, int n_in,
                              void* d_out, int out_size, void* d_ws, size_t ws_size,
                              hipStream_t stream) {
  const float* x = (const float*)d_in[0];     // (128,3,224,224) f32
  const float* W = (const float*)d_in[1];     // (768,3,16,16)  f32
  const float* bias = (const float*)d_in[2];  // (768,)         f32
  float* out = (float*)d_out;                 // (128,196,768)  f32

  unsigned short* A = (unsigned short*)d_ws;                        // 25088*768 bf16
  unsigned short* Wb = (unsigned short*)((char*)d_ws + 38535168);   // 589824 bf16

  convw_kernel<<<576, 256, 0, stream>>>(W, Wb);
  dwt2_kernel<<<4704, 256, 0, stream>>>(x, A);
  gemm_kernel<<<1176, 256, 0, stream>>>(A, Wb, bias, out);
}